// Round 1
// baseline (237.758 us; speedup 1.0000x reference)
//
#include <hip/hip_runtime.h>
#include <hip/hip_cooperative_groups.h>

namespace cg = cooperative_groups;

// FreqLinear fused: prep (Y2 frags + corr) + B-resident GEMM in ONE
// cooperative kernel. grid 256 x 512thr, 1 block/CU (128KB LDS) -> exactly
// co-resident, so grid.sync() is legal. The idx HBM stream (the 64 MB
// roofline term) is started BEFORE the prep math so prep's ~3us hides under
// it; grid.sync() publishes Y2f/corr across XCDs (release/acquire fences).
// GEMM structure unchanged from v5: B-resident LDS, 2-deep idx prefetch,
// one barrier per chunk, XOR-swizzled B layout.

typedef __attribute__((ext_vector_type(8))) short bf16x8;   // 8 bf16
typedef __attribute__((ext_vector_type(4))) float f32x4;

#define K_TOT   2048
#define N_TOT   8192
#define NT      32        // cols per block
#define NCHUNK  8         // K chunks of 256
#define SPC     8         // ksteps (K=32) per chunk
#define LDS_CH  16384     // bytes per chunk region: 32 cols * 256 * 2B

__device__ __forceinline__ unsigned short f2bf_rn(float f) {
    unsigned u = __float_as_uint(f);
    u += 0x7FFFu + ((u >> 16) & 1u);
    return (unsigned short)(u >> 16);
}
// two ints (0..255) -> exact floats -> packed bf16 pair (truncation exact)
__device__ __forceinline__ unsigned pack2(int a, int b) {
    unsigned ua = __float_as_uint((float)a);
    unsigned ub = __float_as_uint((float)b);
    return __builtin_amdgcn_perm(ub, ua, 0x07060302u);
}

__device__ __forceinline__ void lds_barrier() {
    asm volatile("" ::: "memory");
    __builtin_amdgcn_s_waitcnt(0xC07F);   // lgkmcnt(0); vmcnt=63, expcnt=7
    __builtin_amdgcn_s_barrier();
    asm volatile("" ::: "memory");
}

__global__ __launch_bounds__(512, 2) void fused_kernel(
    const float* __restrict__ x, const int* __restrict__ idx,
    const float* __restrict__ c_min, const float* __restrict__ c_range,
    const float* __restrict__ bias, unsigned short* __restrict__ Y2f,
    float* __restrict__ corr, float* __restrict__ out)
{
    __shared__ char lds[NCHUNK * LDS_CH];     // 128 KB, B-resident
    __shared__ float Bk[8][16];
    __shared__ float scmin[8];
    __shared__ float ss[8];
    __shared__ float red[8];

    const int tid  = threadIdx.x;
    const int wave = tid >> 6;
    const int lane = tid & 63;
    const int fr   = lane & 15;
    const int fq   = lane >> 4;
    const int m    = blockIdx.x;          // prep row AND gemm col-block id
    const int o0   = m * NT;

    // staging: thread -> col scol, int-quads skq + r*16 (r = 0..3)
    const int scol = tid >> 4;      // 0..31
    const int skq  = tid & 15;      // 0..15
    const int* sBase = idx + (long)(o0 + scol) * K_TOT + skq * 4;

    int4 S[2][4];    // 2 chunks in flight

#define STAGE_LOAD(ch)                                                    \
    {                                                                     \
        _Pragma("unroll")                                                 \
        for (int r = 0; r < 4; ++r)                                       \
            S[(ch) & 1][r] = *(const int4*)(sBase + (ch) * 256 + r * 64); \
    }

    // XOR-swizzled chunk region: addr(col, kq) = col*512 + ((kq>>1)^col)*16
    //                                            + (kq&1)*8   (kq = int-quad)
#define STAGE_WRITE(ch)                                                   \
    {                                                                     \
        char* buf = lds + (ch) * LDS_CH;                                  \
        _Pragma("unroll")                                                 \
        for (int r = 0; r < 4; ++r) {                                     \
            const int kq = skq + r * 16;                                  \
            uint2 w;                                                      \
            w.x = pack2(S[(ch) & 1][r].x, S[(ch) & 1][r].y);              \
            w.y = pack2(S[(ch) & 1][r].z, S[(ch) & 1][r].w);              \
            *(uint2*)(buf + scol * 512 + (((kq >> 1) ^ scol) * 16)        \
                      + (kq & 1) * 8) = w;                                \
        }                                                                 \
    }

#define BREAD(buf, s, g)                                                  \
    (*(const bf16x8*)((buf) + (g * 16 + fr) * 512 +                       \
                      ((((s) * 4 + fq) ^ (g * 16 + fr)) * 16)))

    // ---- phase 0: start the idx HBM stream immediately (2 chunks deep).
    // idx loading has no dependence on prep, so it runs under the prep math.
    STAGE_LOAD(0)
    STAGE_LOAD(1)

    // ---- phase 1: prep for row m (Y2 frag-order bf16 + corr[m]) ----
    if (tid < 128) {
        int k = tid >> 4, t = tid & 15;
        float v = cosf(3.14159265358979f * (t + 0.5f) * (float)k / 16.0f)
                  * 0.353553390593274f;                 // sqrt(2/16)
        if (k == 0) v *= 0.707106781186548f;            // 1/sqrt(2)
        Bk[k][t] = v;
    }
    if (tid < 8) {
        scmin[tid] = c_min[tid];
        ss[tid] = c_range[tid] * (1.0f / 255.0f);
    }
    __syncthreads();

    float partial = 0.0f;
    if (tid < 256) {
        const float* xp = x + (long)m * 4096 + tid * 16;
        float xs[16];
#pragma unroll
        for (int q = 0; q < 4; ++q) {
            float4 v = *(const float4*)(xp + q * 4);
            xs[q * 4 + 0] = v.x; xs[q * 4 + 1] = v.y;
            xs[q * 4 + 2] = v.z; xs[q * 4 + 3] = v.w;
        }
        unsigned short yo[8];
#pragma unroll
        for (int k = 0; k < 8; ++k) {
            float y = 0.0f;
#pragma unroll
            for (int t = 0; t < 16; ++t) y += xs[t] * Bk[k][t];
            partial += y * scmin[k];
            yo[k] = f2bf_rn(y * ss[k]);
        }
        uint4 pk;
        pk.x = (unsigned)yo[0] | ((unsigned)yo[1] << 16);
        pk.y = (unsigned)yo[2] | ((unsigned)yo[3] << 16);
        pk.z = (unsigned)yo[4] | ((unsigned)yo[5] << 16);
        pk.w = (unsigned)yo[6] | ((unsigned)yo[7] << 16);
        // frag-order store: kc = tid>>2, fq = tid&3, mg = m>>4, fr = m&15
        const int mg = m >> 4, frm = m & 15, kc = tid >> 2, fqp = tid & 3;
        unsigned short* dst =
            Y2f + ((long)((mg * 64 + kc) * 64) + fqp * 16 + frm) * 8;
        *(uint4*)dst = pk;
    }
#pragma unroll
    for (int off = 32; off > 0; off >>= 1)
        partial += __shfl_down(partial, off, 64);
    if (lane == 0) red[wave] = partial;
    __syncthreads();
    if (tid == 0) {
        float csum = 0.0f;
#pragma unroll
        for (int i = 0; i < 8; ++i) csum += red[i];
        corr[m] = csum;
    }

    // ---- phase 2: publish Y2f/corr grid-wide (cross-XCD L2 fences) ----
    __threadfence();                 // release: drain Y2f/corr writes to HBM
    cg::this_grid().sync();
    __threadfence();                 // acquire: invalidate stale cached lines

    // ---- phase 3: B-resident GEMM (unchanged v5 structure) ----
    const bf16x8* aF[2];
    aF[0] = (const bf16x8*)Y2f + (long)((wave * 2 + 0) * 64) * 64 + lane;
    aF[1] = (const bf16x8*)Y2f + (long)((wave * 2 + 1) * 64) * 64 + lane;

    f32x4 acc[2][2] = {{{0.f,0.f,0.f,0.f},{0.f,0.f,0.f,0.f}},
                       {{0.f,0.f,0.f,0.f},{0.f,0.f,0.f,0.f}}};

    STAGE_WRITE(0)
    lds_barrier();

#pragma unroll
    for (int c = 0; c < NCHUNK; ++c) {
        // 1) A-burst for chunk c (L2-hot) -- BEFORE new HBM loads, so MFMA
        //    waits (vmcnt) never drain the idx stream
        bf16x8 a[SPC][2];
#pragma unroll
        for (int s = 0; s < SPC; ++s) {
            a[s][0] = aF[0][(c * SPC + s) * 64];
            a[s][1] = aF[1][(c * SPC + s) * 64];
        }
        // 2) keep the idx stream 2 chunks deep
        if (c + 2 < NCHUNK) STAGE_LOAD(c + 2)
        // 3) publish chunk c+1
        if (c + 1 < NCHUNK) STAGE_WRITE(c + 1)
        lds_barrier();
        // 4) compute chunk c (region c is immutable from here on)
        {
            const char* buf = lds + c * LDS_CH;
            bf16x8 b[2][2];
            b[0][0] = BREAD(buf, 0, 0);
            b[0][1] = BREAD(buf, 0, 1);
#pragma unroll
            for (int s = 0; s < SPC; ++s) {
                if (s + 1 < SPC) {
                    b[(s + 1) & 1][0] = BREAD(buf, (s + 1), 0);
                    b[(s + 1) & 1][1] = BREAD(buf, (s + 1), 1);
                }
#pragma unroll
                for (int mt = 0; mt < 2; ++mt)
#pragma unroll
                    for (int g = 0; g < 2; ++g)
                        acc[mt][g] = __builtin_amdgcn_mfma_f32_16x16x32_bf16(
                            a[s][mt], b[s & 1][g], acc[mt][g], 0, 0, 0);
            }
        }
    }

    // epilogue: D layout col=lane&15, row=(lane>>4)*4+reg
#pragma unroll
    for (int mt = 0; mt < 2; ++mt) {
#pragma unroll
        for (int g = 0; g < 2; ++g) {
            const int col = o0 + g * 16 + fr;
            const float bv = bias[col];
            const int row0 = (wave * 2 + mt) * 16 + fq * 4;
#pragma unroll
            for (int r = 0; r < 4; ++r)
                out[(long)(row0 + r) * N_TOT + col] =
                    acc[mt][g][r] + bv + corr[row0 + r];
        }
    }
#undef STAGE_LOAD
#undef STAGE_WRITE
#undef BREAD
}

extern "C" void kernel_launch(void* const* d_in, const int* in_sizes, int n_in,
                              void* d_out, int out_size, void* d_ws, size_t ws_size,
                              hipStream_t stream) {
    const float* x       = (const float*)d_in[0];   // [32,8,4096]
    const int*   idx     = (const int*)d_in[1];     // [2097152, 8]
    const float* c_min   = (const float*)d_in[2];   // [8]
    const float* c_range = (const float*)d_in[3];   // [8]
    const float* bias    = (const float*)d_in[4];   // [8192]
    float* out = (float*)d_out;                     // [256, 8192]

    unsigned short* Y2f = (unsigned short*)d_ws;                   // 1 MB
    float* corr = (float*)((char*)d_ws + (size_t)256 * K_TOT * 2); // 256 fp32

    void* args[] = {(void*)&x, (void*)&idx, (void*)&c_min, (void*)&c_range,
                    (void*)&bias, (void*)&Y2f, (void*)&corr, (void*)&out};
    hipLaunchCooperativeKernel((const void*)fused_kernel, dim3(256), dim3(512),
                               args, 0, stream);
}

// Round 3
// 119.062 us; speedup vs baseline: 1.9969x; 1.9969x over previous
//
#include <hip/hip_runtime.h>

// FreqLinear: out = Y2 @ float(idx)^T + corr[m] + bias[o], K = 2048.
// GEMM v5: B-RESIDENT LDS. grid 256 x 512thr (8 waves), block = 32 cols x
// all 256 rows. The block's whole B operand (32x2048 bf16 = 128 KB) lives in
// LDS; each 256-K chunk region is written once, never evicted, so staging
// never waits on consumers. Per-iteration order:
//    A_burst(c) -> idx_load(c+2) -> write(c+1) -> barrier -> MFMA(c)
// keeps A-frag vmcnt waits AHEAD of the HBM idx stream (wait = vmcnt(4),
// the idx loads stay in flight across chunks; 2-deep = 8 KB/wave, 64 KB/CU
// outstanding >> needed to saturate this CU's HBM share). One barrier per
// chunk (s_barrier + lgkmcnt(0) only, no vmcnt drain).
//
// NOTE (round-1 post-mortem): do NOT fuse these two kernels with a
// cooperative grid.sync -- measured +115us (135us fused vs ~17us split):
// device-scope fences + cross-XCD grid barrier dominate. Two launches on
// the stream are the fast path.

typedef __attribute__((ext_vector_type(8))) short bf16x8;   // 8 bf16
typedef __attribute__((ext_vector_type(4))) float f32x4;

#define K_TOT   2048
#define N_TOT   8192
#define NT      32        // cols per block
#define NCHUNK  8         // K chunks of 256
#define SPC     8         // ksteps (K=32) per chunk
#define LDS_CH  16384     // bytes per chunk region: 32 cols * 256 * 2B

__device__ __forceinline__ unsigned short f2bf_rn(float f) {
    unsigned u = __float_as_uint(f);
    u += 0x7FFFu + ((u >> 16) & 1u);
    return (unsigned short)(u >> 16);
}
// two ints (0..255) -> exact floats -> packed bf16 pair (truncation exact)
__device__ __forceinline__ unsigned pack2(int a, int b) {
    unsigned ua = __float_as_uint((float)a);
    unsigned ub = __float_as_uint((float)b);
    return __builtin_amdgcn_perm(ub, ua, 0x07060302u);
}

__device__ __forceinline__ void lds_barrier() {
    asm volatile("" ::: "memory");
    __builtin_amdgcn_s_waitcnt(0xC07F);   // lgkmcnt(0); vmcnt=63, expcnt=7
    __builtin_amdgcn_s_barrier();
    asm volatile("" ::: "memory");
}

// ---------------- Kernel A: build Y2f (bf16, frag order) + corr ------------
__global__ __launch_bounds__(256) void prep_kernel(
    const float* __restrict__ x, const float* __restrict__ c_min,
    const float* __restrict__ c_range, unsigned short* __restrict__ Y2f,
    float* __restrict__ corr)
{
    __shared__ float Bk[8][16];
    __shared__ float scmin[8];
    __shared__ float ss[8];
    __shared__ float red[4];
    const int tid = threadIdx.x;
    const int m = blockIdx.x;
    if (tid < 128) {
        int k = tid >> 4, t = tid & 15;
        float v = cosf(3.14159265358979f * (t + 0.5f) * (float)k / 16.0f)
                  * 0.353553390593274f;                 // sqrt(2/16)
        if (k == 0) v *= 0.707106781186548f;            // 1/sqrt(2)
        Bk[k][t] = v;
    }
    if (tid < 8) {
        scmin[tid] = c_min[tid];
        ss[tid] = c_range[tid] * (1.0f / 255.0f);
    }
    __syncthreads();

    const float* xp = x + (long)m * 4096 + tid * 16;
    float xs[16];
#pragma unroll
    for (int q = 0; q < 4; ++q) {
        float4 v = *(const float4*)(xp + q * 4);
        xs[q * 4 + 0] = v.x; xs[q * 4 + 1] = v.y;
        xs[q * 4 + 2] = v.z; xs[q * 4 + 3] = v.w;
    }
    float partial = 0.0f;
    unsigned short yo[8];
#pragma unroll
    for (int k = 0; k < 8; ++k) {
        float y = 0.0f;
#pragma unroll
        for (int t = 0; t < 16; ++t) y += xs[t] * Bk[k][t];
        partial += y * scmin[k];
        yo[k] = f2bf_rn(y * ss[k]);
    }
    uint4 pk;
    pk.x = (unsigned)yo[0] | ((unsigned)yo[1] << 16);
    pk.y = (unsigned)yo[2] | ((unsigned)yo[3] << 16);
    pk.z = (unsigned)yo[4] | ((unsigned)yo[5] << 16);
    pk.w = (unsigned)yo[6] | ((unsigned)yo[7] << 16);
    // frag-order store: kc = tid>>2, fq = tid&3, mg = m>>4, fr = m&15
    {
        const int mg = m >> 4, fr = m & 15, kc = tid >> 2, fq = tid & 3;
        unsigned short* dst = Y2f + ((long)((mg * 64 + kc) * 64) + fq * 16 + fr) * 8;
        *(uint4*)dst = pk;
    }
#pragma unroll
    for (int off = 32; off > 0; off >>= 1)
        partial += __shfl_down(partial, off, 64);
    if ((tid & 63) == 0) red[tid >> 6] = partial;
    __syncthreads();
    if (tid == 0) corr[m] = red[0] + red[1] + red[2] + red[3];
}

// ---------------- Kernel B ------------------------------------------------
__global__ __launch_bounds__(512, 2) void gemm_kernel(
    const unsigned short* __restrict__ Y2f, const int* __restrict__ idx,
    const float* __restrict__ bias, const float* __restrict__ corr,
    float* __restrict__ out)
{
    __shared__ char lds[NCHUNK * LDS_CH];     // 128 KB, B-resident

    const int tid  = threadIdx.x;
    const int wave = tid >> 6;
    const int lane = tid & 63;
    const int fr   = lane & 15;
    const int fq   = lane >> 4;
    const int o0   = blockIdx.x * NT;

    // staging: thread -> col scol, int-quads skq + r*16 (r = 0..3)
    const int scol = tid >> 4;      // 0..31
    const int skq  = tid & 15;      // 0..15
    const int* sBase = idx + (long)(o0 + scol) * K_TOT + skq * 4;

    // A frags: mg = wave*2 + mt; frag(mg,kc) at bf16x8 index (mg*64+kc)*64+lane
    const bf16x8* aF[2];
    aF[0] = (const bf16x8*)Y2f + (long)((wave * 2 + 0) * 64) * 64 + lane;
    aF[1] = (const bf16x8*)Y2f + (long)((wave * 2 + 1) * 64) * 64 + lane;

    f32x4 acc[2][2] = {{{0.f,0.f,0.f,0.f},{0.f,0.f,0.f,0.f}},
                       {{0.f,0.f,0.f,0.f},{0.f,0.f,0.f,0.f}}};
    int4 S[2][4];    // 2 chunks in flight

#define STAGE_LOAD(ch)                                                    \
    {                                                                     \
        _Pragma("unroll")                                                 \
        for (int r = 0; r < 4; ++r)                                       \
            S[(ch) & 1][r] = *(const int4*)(sBase + (ch) * 256 + r * 64); \
    }

    // XOR-swizzled chunk region: addr(col, kq) = col*512 + ((kq>>1)^col)*16
    //                                            + (kq&1)*8   (kq = int-quad)
#define STAGE_WRITE(ch)                                                   \
    {                                                                     \
        char* buf = lds + (ch) * LDS_CH;                                  \
        _Pragma("unroll")                                                 \
        for (int r = 0; r < 4; ++r) {                                     \
            const int kq = skq + r * 16;                                  \
            uint2 w;                                                      \
            w.x = pack2(S[(ch) & 1][r].x, S[(ch) & 1][r].y);              \
            w.y = pack2(S[(ch) & 1][r].z, S[(ch) & 1][r].w);              \
            *(uint2*)(buf + scol * 512 + (((kq >> 1) ^ scol) * 16)        \
                      + (kq & 1) * 8) = w;                                \
        }                                                                 \
    }

#define BREAD(buf, s, g)                                                  \
    (*(const bf16x8*)((buf) + (g * 16 + fr) * 512 +                       \
                      ((((s) * 4 + fq) ^ (g * 16 + fr)) * 16)))

    // prologue: stream chunks 0,1; write 0; barrier
    STAGE_LOAD(0)
    STAGE_LOAD(1)
    STAGE_WRITE(0)
    lds_barrier();

#pragma unroll
    for (int c = 0; c < NCHUNK; ++c) {
        // 1) A-burst for chunk c (L2-hot) -- BEFORE new HBM loads, so MFMA
        //    waits (vmcnt(4)) never drain the idx stream
        bf16x8 a[SPC][2];
#pragma unroll
        for (int s = 0; s < SPC; ++s) {
            a[s][0] = aF[0][(c * SPC + s) * 64];
            a[s][1] = aF[1][(c * SPC + s) * 64];
        }
        // 2) keep the idx stream 2 chunks deep
        if (c + 2 < NCHUNK) STAGE_LOAD(c + 2)
        // 3) publish chunk c+1
        if (c + 1 < NCHUNK) STAGE_WRITE(c + 1)
        lds_barrier();
        // 4) compute chunk c (region c is immutable from here on)
        {
            const char* buf = lds + c * LDS_CH;
            bf16x8 b[2][2];
            b[0][0] = BREAD(buf, 0, 0);
            b[0][1] = BREAD(buf, 0, 1);
#pragma unroll
            for (int s = 0; s < SPC; ++s) {
                if (s + 1 < SPC) {
                    b[(s + 1) & 1][0] = BREAD(buf, (s + 1), 0);
                    b[(s + 1) & 1][1] = BREAD(buf, (s + 1), 1);
                }
#pragma unroll
                for (int mt = 0; mt < 2; ++mt)
#pragma unroll
                    for (int g = 0; g < 2; ++g)
                        acc[mt][g] = __builtin_amdgcn_mfma_f32_16x16x32_bf16(
                            a[s][mt], b[s & 1][g], acc[mt][g], 0, 0, 0);
            }
        }
    }

    // epilogue: D layout col=lane&15, row=(lane>>4)*4+reg
#pragma unroll
    for (int mt = 0; mt < 2; ++mt) {
#pragma unroll
        for (int g = 0; g < 2; ++g) {
            const int col = o0 + g * 16 + fr;
            const float bv = bias[col];
            const int row0 = (wave * 2 + mt) * 16 + fq * 4;
#pragma unroll
            for (int r = 0; r < 4; ++r)
                out[(long)(row0 + r) * N_TOT + col] =
                    acc[mt][g][r] + bv + corr[row0 + r];
        }
    }
#undef STAGE_LOAD
#undef STAGE_WRITE
#undef BREAD
}

extern "C" void kernel_launch(void* const* d_in, const int* in_sizes, int n_in,
                              void* d_out, int out_size, void* d_ws, size_t ws_size,
                              hipStream_t stream) {
    const float* x       = (const float*)d_in[0];   // [32,8,4096]
    const int*   idx     = (const int*)d_in[1];     // [2097152, 8]
    const float* c_min   = (const float*)d_in[2];   // [8]
    const float* c_range = (const float*)d_in[3];   // [8]
    const float* bias    = (const float*)d_in[4];   // [8192]
    float* out = (float*)d_out;                     // [256, 8192]

    unsigned short* Y2f = (unsigned short*)d_ws;                   // 1 MB
    float* corr = (float*)((char*)d_ws + (size_t)256 * K_TOT * 2); // 256 fp32

    prep_kernel<<<256, 256, 0, stream>>>(x, c_min, c_range, Y2f, corr);
    gemm_kernel<<<256, 512, 0, stream>>>(Y2f, idx, bias, corr, out);
}